// Round 22
// baseline (64.499 us; speedup 1.0000x reference)
//
#include <hip/hip_runtime.h>
#include <cstdint>
#include <cstddef>

#define BATCH 4
#define CIN   512
#define NPIX  1024
#define HEADS 16
#define DH    32
#define DATTN 512
#define O_QKV 1536

typedef unsigned short u16;
typedef __bf16 bf16x4 __attribute__((ext_vector_type(4)));
typedef __bf16 bf16x8 __attribute__((ext_vector_type(8)));
typedef float  f32x4  __attribute__((ext_vector_type(4)));

typedef const __attribute__((address_space(1))) void g1_t;
typedef __attribute__((address_space(3))) void l3_t;

#if defined(__has_builtin)
#if __has_builtin(__builtin_amdgcn_exp2f)
#define EXP2(x) __builtin_amdgcn_exp2f(x)
#endif
#endif
#ifndef EXP2
#define EXP2(x) __expf((x) * 0.6931471805599453f)
#endif

__device__ __forceinline__ u16 f2bf(float f) {
  unsigned u = __float_as_uint(f);
  u += 0x7fffu + ((u >> 16) & 1u);
  return (u16)(u >> 16);
}

// async global->LDS, 16B per lane; lp must be wave-uniform (HW: base + lane*16)
__device__ __forceinline__ void gl_lds16(const void* gp, void* lp) {
  __builtin_amdgcn_global_load_lds((g1_t*)gp, (l3_t*)lp, 16, 0, 0);
}

// ---------------------------------------------------------------------------
// prep_fused: blocks 0..511 = x [B][C][N] f32 -> xt [B][N][C] bf16 (LDS
// transpose); blocks 512..1535 = w_qkv + w_proj f32 -> bf16. One launch.
// ---------------------------------------------------------------------------
__global__ __launch_bounds__(256) void prep_fused(const float* __restrict__ x,
                                                  const float* __restrict__ w1,
                                                  const float* __restrict__ w2,
                                                  u16* __restrict__ xt,
                                                  u16* __restrict__ o1,
                                                  u16* __restrict__ o2) {
  const int t = threadIdx.x;
  if (blockIdx.x < 512) {
    __shared__ float sT[64][65];
    const int q  = blockIdx.x;
    const int n0 = (q & 15) << 6;
    const int c0 = ((q >> 4) & 7) << 6;
    const int b  = q >> 7;
    const float* xb = x + ((size_t)b * CIN + c0) * NPIX + n0;
#pragma unroll
    for (int i = 0; i < 4; ++i) {
      int r   = i * 16 + (t >> 4);
      int col = (t & 15) << 2;
      float4 v = *reinterpret_cast<const float4*>(&xb[(size_t)r * NPIX + col]);
      sT[r][col + 0] = v.x; sT[r][col + 1] = v.y;
      sT[r][col + 2] = v.z; sT[r][col + 3] = v.w;
    }
    __syncthreads();
#pragma unroll
    for (int i = 0; i < 2; ++i) {
      int nl = t >> 2;
      int ch = (t & 3) + (i << 2);
      u16 tmp[8];
#pragma unroll
      for (int e = 0; e < 8; ++e) tmp[e] = f2bf(sT[(ch << 3) + e][nl]);
      *reinterpret_cast<uint4*>(&xt[((size_t)b * NPIX + n0 + nl) * CIN + c0 + (ch << 3)]) =
          *reinterpret_cast<uint4*>(tmp);
    }
  } else {
    const int idx = (blockIdx.x - 512) * 256 + t;   // float4 index
    const int n1 = (O_QKV * CIN) >> 2;              // 196608
    float4 v = (idx < n1) ? reinterpret_cast<const float4*>(w1)[idx]
                          : reinterpret_cast<const float4*>(w2)[idx - n1];
    uint2 pk = make_uint2((unsigned)f2bf(v.x) | ((unsigned)f2bf(v.y) << 16),
                          (unsigned)f2bf(v.z) | ((unsigned)f2bf(v.w) << 16));
    if (idx < n1) reinterpret_cast<uint2*>(o1)[idx] = pk;
    else          reinterpret_cast<uint2*>(o2)[idx - n1] = pk;
  }
}

// ---------------------------------------------------------------------------
// QKV GEMM (MFMA): M-tile=96 (one head), N-tile=128, BK=64, 4 waves.
// Epilogue: +bias, bf16; q PRE-SCALED by scale*log2e (attn uses exp2 domain).
// qt/kt [b][h][n][32], vt [b][h][d][n].
// ---------------------------------------------------------------------------
__global__ __launch_bounds__(256) void gemm_qkv_mfma(const u16* __restrict__ wq,
                                                     const u16* __restrict__ xt,
                                                     const float* __restrict__ bias,
                                                     u16* __restrict__ qt,
                                                     u16* __restrict__ kt,
                                                     u16* __restrict__ vt) {
  __shared__ __align__(16) u16 sA[96 * 64];
  __shared__ __align__(16) u16 sB[128 * 64];
  const int t  = threadIdx.x;
  const int w  = t >> 6, l = t & 63, g = l >> 4, ln = l & 15;
  const int n0 = blockIdx.x * 128;
  const int h  = blockIdx.y;
  const int b  = blockIdx.z;
  const int wm = w >> 1, wn = w & 1;

  const u16* wbase = wq + (size_t)h * 96 * CIN;
  const u16* xbase = xt + ((size_t)b * NPIX + n0) * CIN;

  f32x4 acc[3][4];
#pragma unroll
  for (int mi = 0; mi < 3; ++mi)
#pragma unroll
    for (int ni = 0; ni < 4; ++ni) acc[mi][ni] = {0.f, 0.f, 0.f, 0.f};

  for (int k0 = 0; k0 < CIN; k0 += 64) {
#pragma unroll
    for (int i = 0; i < 3; ++i) {
      int chunk = i * 256 + (w << 6) + l;
      gl_lds16(wbase + ((size_t)(chunk >> 3)) * CIN + k0 + ((chunk & 7) << 3),
               (char*)sA + i * 4096 + (w << 10));
    }
#pragma unroll
    for (int i = 0; i < 4; ++i) {
      int chunk = i * 256 + (w << 6) + l;
      gl_lds16(xbase + ((size_t)(chunk >> 3)) * CIN + k0 + ((chunk & 7) << 3),
               (char*)sB + i * 4096 + (w << 10));
    }
    __syncthreads();
#pragma unroll
    for (int kk = 0; kk < 64; kk += 32) {
      bf16x8 af[3], bfr[4];
#pragma unroll
      for (int mi = 0; mi < 3; ++mi)
        af[mi] = *reinterpret_cast<const bf16x8*>(&sA[(48 * wm + 16 * mi + ln) * 64 + kk + (g << 3)]);
#pragma unroll
      for (int ni = 0; ni < 4; ++ni)
        bfr[ni] = *reinterpret_cast<const bf16x8*>(&sB[((wn << 6) + (ni << 4) + ln) * 64 + kk + (g << 3)]);
#pragma unroll
      for (int mi = 0; mi < 3; ++mi)
#pragma unroll
        for (int ni = 0; ni < 4; ++ni)
          acc[mi][ni] = __builtin_amdgcn_mfma_f32_16x16x32_bf16(af[mi], bfr[ni], acc[mi][ni], 0, 0, 0);
    }
    __syncthreads();
  }

  const float QSC = 0.17677669529663687f * 1.4426950408889634f;  // scale*log2e
  const float* bh = bias + h * 96;
#pragma unroll
  for (int mi = 0; mi < 3; ++mi) {
    const int sec = 48 * wm + 16 * mi;
    const int rb  = sec + (g << 2);
    const float b0 = bh[rb + 0], b1 = bh[rb + 1], b2 = bh[rb + 2], b3 = bh[rb + 3];
#pragma unroll
    for (int ni = 0; ni < 4; ++ni) {
      const int n = n0 + (wn << 6) + (ni << 4) + ln;
      f32x4 a = acc[mi][ni];
      float v0 = a[0] + b0, v1 = a[1] + b1, v2 = a[2] + b2, v3 = a[3] + b3;
      if (sec < 32) { v0 *= QSC; v1 *= QSC; v2 *= QSC; v3 *= QSC; }
      u16 e0 = f2bf(v0), e1 = f2bf(v1), e2 = f2bf(v2), e3 = f2bf(v3);
      if (sec < 32) {
        const int d = sec + (g << 2);
        uint2 pk = make_uint2((unsigned)e0 | ((unsigned)e1 << 16),
                              (unsigned)e2 | ((unsigned)e3 << 16));
        *reinterpret_cast<uint2*>(&qt[(((size_t)(b * HEADS + h)) * NPIX + n) * DH + d]) = pk;
      } else if (sec < 64) {
        const int d = sec - 32 + (g << 2);
        uint2 pk = make_uint2((unsigned)e0 | ((unsigned)e1 << 16),
                              (unsigned)e2 | ((unsigned)e3 << 16));
        *reinterpret_cast<uint2*>(&kt[(((size_t)(b * HEADS + h)) * NPIX + n) * DH + d]) = pk;
      } else {
        const int d = sec - 64 + (g << 2);
        u16* vp = &vt[(((size_t)(b * HEADS + h)) * DH + d) * NPIX + n];
        vp[0] = e0; vp[NPIX] = e1; vp[2 * NPIX] = e2; vp[3 * NPIX] = e3;
      }
    }
  }
}

// ---------------------------------------------------------------------------
// MFMA flash attention v22 = r20 wave math (verified, absmax 4.88e-4) with
// 32-row i-tiles / 128-thr blocks -> grid 1024 = 4 blocks/CU (fixes r20's
// 2-blocks/CU occupancy defect; r17 vs r18 showed half-rel-stream pays only
// at >=4 blocks/CU). Each wave: 2 batches (reg-level rel reuse), full j
// (16 steps of 64), one __syncthreads/step.
// Staging: 128 thr x 2 chunks per tile (chunks t and t+128). Row r+16 leaves
// both XOR swizzles invariant -> second chunk = +32 j-rows (K: +1024 u16) /
// +16 d-rows (V: +16*NPIX u16) in source, +2048B in LDS.
// Grid decode: xcd=bid&7, sl=bid>>3; bp=sl&1 (siblings bid-dist 8 -> same
// XCD, adjacent -> rel L2 reuse), i0=((sl>>1)&31)<<5, h=(xcd<<1)|(sl>>6).
// K LDS per (buf,b2): [32 packed rows r=j>>1][8 slots 16B], slot^=(r&7)^((r>>3)&1).
// V LDS per (buf,b2): [32 d][8 slots 16B], slot^=(d&7).
// sP per wave: [16 rows][8 slots 16B], slot^=(row&7); b64 half-slot writes.
// LDS 34KB -> 4 blocks/CU; (128,2): VGPR cap generous, no spill.
// ---------------------------------------------------------------------------
__global__ __launch_bounds__(128, 2) void attn_mfma(const u16* __restrict__ qt,
                                                    const u16* __restrict__ kt,
                                                    const u16* __restrict__ vt,
                                                    const float* __restrict__ rel,
                                                    u16* __restrict__ aout) {
  __shared__ __align__(16) u16 sK[2][2][2048];   // [buf][b2][32r][8slot][8] 16KB
  __shared__ __align__(16) u16 sV[2][2][2048];   // [buf][b2][32d][8slot][8] 16KB
  __shared__ __align__(16) u16 sP[2][1024];      // per-wave [16][8slot][8]   4KB

  const int t  = threadIdx.x;
  const int w  = t >> 6, l = t & 63, g = l >> 4, ln = l & 15;
  const int bid = blockIdx.x;
  const int xcd = bid & 7, sl = bid >> 3;   // sl 0..127
  const int bp  = sl & 1;                   // batch pair
  const int i0  = ((sl >> 1) & 31) << 5;    // 32-row i-tile
  const int h   = (xcd << 1) | (sl >> 6);
  const int iw  = w;                        // i-segment (16 rows), w in {0,1}

  const size_t bh0 = (size_t)((bp * 2 + 0) * HEADS + h);
  const size_t bh1 = (size_t)((bp * 2 + 1) * HEADS + h);

  // staging (r20 mapping): thread t covers chunks t and t+128 of each tile.
  const int sc_r  = t >> 3;
  const int sc_kc = (t & 7) ^ (sc_r & 7) ^ ((sc_r >> 3) & 1);  // K logical chunk
  const int sc_vc = (t & 7) ^ (sc_r & 7);                      // V logical chunk
  const size_t kro = ((size_t)((sc_r << 1) | (sc_kc >> 2))) * DH + ((sc_kc & 3) << 3);
  const u16* ksrc0 = kt + bh0 * NPIX * DH + kro;
  const u16* ksrc1 = kt + bh1 * NPIX * DH + kro;
  const u16* vsrc0 = vt + (bh0 * DH + sc_r) * NPIX + (sc_vc << 3);
  const u16* vsrc1 = vt + (bh1 * DH + sc_r) * NPIX + (sc_vc << 3);
  char* kBase = (char*)&sK[0][0][0] + (w << 10);   // + p*8192 + b2*4096 (+2048 for chunk2)
  char* vBase = (char*)&sV[0][0][0] + (w << 10);

#define STAGE(s_, p_) do {                                                       \
    gl_lds16(ksrc0 + (size_t)(s_) * 2048,        kBase + (p_) * 8192);           \
    gl_lds16(ksrc0 + (size_t)(s_) * 2048 + 1024, kBase + (p_) * 8192 + 2048);    \
    gl_lds16(ksrc1 + (size_t)(s_) * 2048,        kBase + (p_) * 8192 + 4096);    \
    gl_lds16(ksrc1 + (size_t)(s_) * 2048 + 1024, kBase + (p_) * 8192 + 6144);    \
    gl_lds16(vsrc0 + (size_t)(s_) * 64,             vBase + (p_) * 8192);        \
    gl_lds16(vsrc0 + (size_t)(s_) * 64 + 16 * NPIX, vBase + (p_) * 8192 + 2048); \
    gl_lds16(vsrc1 + (size_t)(s_) * 64,             vBase + (p_) * 8192 + 4096); \
    gl_lds16(vsrc1 + (size_t)(s_) * 64 + 16 * NPIX, vBase + (p_) * 8192 + 6144); \
  } while (0)

  STAGE(0, 0);

  // Q fragments (pre-scaled by scale*log2e): lane -> row i0+16*iw+ln, k=8g..
  bf16x8 qf0 = *reinterpret_cast<const bf16x8*>(
      qt + (bh0 * NPIX + i0 + (iw << 4) + ln) * DH + (g << 3));
  bf16x8 qf1 = *reinterpret_cast<const bf16x8*>(
      qt + (bh1 * NPIX + i0 + (iw << 4) + ln) * DH + (g << 3));

  // rel: rows i0+16iw+4g+v, cols s*64 + 4ln + (0..3) -- loaded ONCE, used x2
  const float* relp = rel + ((size_t)h * NPIX + i0 + (iw << 4) + (g << 2)) * NPIX +
                      (ln << 2);
  f32x4 relA4[4], relB4[4];
#pragma unroll
  for (int v = 0; v < 4; ++v)
    relA4[v] = *reinterpret_cast<const f32x4*>(relp + (size_t)v * NPIX);

  f32x4 vzero = {0.f, 0.f, 0.f, 0.f};
  f32x4 accO0[2] = {vzero, vzero};
  f32x4 accO1[2] = {vzero, vzero};
  f32x4 l_lane0 = vzero, l_lane1 = vzero;

  u16* sPw = &sP[w][0];
  const float LOG2E = 1.4426950408889634f;

  for (int s = 0; s < 16; ++s) {
    const int p = s & 1;
    __syncthreads();                        // buf p staged; buf p^1 free
    if (s < 15) {
      STAGE(s + 1, p ^ 1);
#pragma unroll
      for (int v = 0; v < 4; ++v)
        relB4[v] = *reinterpret_cast<const f32x4*>(relp + (size_t)v * NPIX + ((s + 1) << 6));
    }

#pragma unroll
    for (int b2 = 0; b2 < 2; ++b2) {
      const u16* Kb = &sK[p][b2][0];
      const u16* Vb = &sV[p][b2][0];
      const bf16x8 qf = b2 ? qf1 : qf0;

      // ---- S' = Q'^T K: fragment jj covers cols j = 4*ln + jj ----
      f32x4 sfr[4];
      __builtin_amdgcn_s_setprio(1);
#pragma unroll
      for (int jj = 0; jj < 4; ++jj) {
        const int r  = (ln << 1) + (jj >> 1);
        const int ks = ((((jj & 1) << 2) | g) ^ (r & 7)) ^ ((r >> 3) & 1);
        bf16x8 kf = *reinterpret_cast<const bf16x8*>(Kb + r * 64 + ks * 8);
        sfr[jj] = __builtin_amdgcn_mfma_f32_16x16x32_bf16(qf, kf, vzero, 0, 0, 0);
      }
      __builtin_amdgcn_s_setprio(0);

      // ---- P = exp2(S' + rel*log2e); swizzled b64 write per row ----
#pragma unroll
      for (int v = 0; v < 4; ++v) {
        float p0 = EXP2(fmaf(relA4[v][0], LOG2E, sfr[0][v]));
        float p1 = EXP2(fmaf(relA4[v][1], LOG2E, sfr[1][v]));
        float p2 = EXP2(fmaf(relA4[v][2], LOG2E, sfr[2][v]));
        float p3 = EXP2(fmaf(relA4[v][3], LOG2E, sfr[3][v]));
        if (b2) l_lane1[v] += (p0 + p1) + (p2 + p3);
        else    l_lane0[v] += (p0 + p1) + (p2 + p3);
        bf16x4 pk;
        pk[0] = (__bf16)p0; pk[1] = (__bf16)p1; pk[2] = (__bf16)p2; pk[3] = (__bf16)p3;
        const int rw = (g << 2) + v;
        *reinterpret_cast<bf16x4*>(
            sPw + rw * 64 + ((((ln >> 1) ^ (rw & 7)) << 3) | ((ln & 1) << 2))) = pk;
      }

      // ---- PV: acc[dc] += P(kc) x V(kc,dc) ----
      __builtin_amdgcn_s_setprio(1);
#pragma unroll
      for (int kc = 0; kc < 2; ++kc) {
        const int lc = (kc << 2) | g;
        bf16x8 pa = *reinterpret_cast<const bf16x8*>(sPw + ln * 64 + ((lc ^ (ln & 7)) << 3));
#pragma unroll
        for (int dc = 0; dc < 2; ++dc) {
          const int d  = (dc << 4) + ln;
          const int vs = lc ^ (d & 7);
          bf16x8 vf = *reinterpret_cast<const bf16x8*>(Vb + d * 64 + vs * 8);
          if (b2) accO1[dc] = __builtin_amdgcn_mfma_f32_16x16x32_bf16(pa, vf, accO1[dc], 0, 0, 0);
          else    accO0[dc] = __builtin_amdgcn_mfma_f32_16x16x32_bf16(pa, vf, accO0[dc], 0, 0, 0);
        }
      }
      __builtin_amdgcn_s_setprio(0);
    }

    if (s < 15) {
#pragma unroll
      for (int v = 0; v < 4; ++v) relA4[v] = relB4[v];
    }
  }
#undef STAGE

  // ---- epilogue: shuffle-reduce l, divide, bf16 write [b][n][c], x2 ----
#pragma unroll
  for (int v = 0; v < 4; ++v) {
    float ls = l_lane0[v];
    ls += __shfl_xor(ls, 1);
    ls += __shfl_xor(ls, 2);
    ls += __shfl_xor(ls, 4);
    ls += __shfl_xor(ls, 8);
    const float inv = 1.f / ls;
    const size_t row = (size_t)(bp * 2 + 0) * NPIX + i0 + (iw << 4) + (g << 2) + v;
    aout[row * DATTN + (h << 5) + ln]      = f2bf(accO0[0][v] * inv);
    aout[row * DATTN + (h << 5) + 16 + ln] = f2bf(accO0[1][v] * inv);
  }
#pragma unroll
  for (int v = 0; v < 4; ++v) {
    float ls = l_lane1[v];
    ls += __shfl_xor(ls, 1);
    ls += __shfl_xor(ls, 2);
    ls += __shfl_xor(ls, 4);
    ls += __shfl_xor(ls, 8);
    const float inv = 1.f / ls;
    const size_t row = (size_t)(bp * 2 + 1) * NPIX + i0 + (iw << 4) + (g << 2) + v;
    aout[row * DATTN + (h << 5) + ln]      = f2bf(accO1[0][v] * inv);
    aout[row * DATTN + (h << 5) + 16 + ln] = f2bf(accO1[1][v] * inv);
  }
}

// ---------------------------------------------------------------------------
// Proj GEMM (MFMA): out[b][o][n] = sum_k Wp[o,k] * A[b][n][k] + bias[o], f32 out.
// ---------------------------------------------------------------------------
__global__ __launch_bounds__(256) void gemm_proj_mfma(const u16* __restrict__ wp,
                                                      const u16* __restrict__ at,
                                                      const float* __restrict__ bias,
                                                      float* __restrict__ out) {
  __shared__ __align__(16) u16 sA[64 * 64];
  __shared__ __align__(16) u16 sB[128 * 64];
  const int t  = threadIdx.x;
  const int w  = t >> 6, l = t & 63, g = l >> 4, ln = l & 15;
  const int n0 = blockIdx.x * 128;
  const int o0 = blockIdx.y * 64;
  const int b  = blockIdx.z;
  const int wm = w >> 1, wn = w & 1;

  const u16* wbase = wp + (size_t)o0 * DATTN;
  const u16* abase = at + ((size_t)b * NPIX + n0) * DATTN;

  f32x4 acc[2][4];
#pragma unroll
  for (int mi = 0; mi < 2; ++mi)
#pragma unroll
    for (int ni = 0; ni < 4; ++ni) acc[mi][ni] = {0.f, 0.f, 0.f, 0.f};

  for (int k0 = 0; k0 < DATTN; k0 += 64) {
#pragma unroll
    for (int i = 0; i < 2; ++i) {
      int chunk = i * 256 + (w << 6) + l;
      gl_lds16(wbase + ((size_t)(chunk >> 3)) * DATTN + k0 + ((chunk & 7) << 3),
               (char*)sA + i * 4096 + (w << 10));
    }
#pragma unroll
    for (int i = 0; i < 4; ++i) {
      int chunk = i * 256 + (w << 6) + l;
      gl_lds16(abase + ((size_t)(chunk >> 3)) * DATTN + k0 + ((chunk & 7) << 3),
               (char*)sB + i * 4096 + (w << 10));
    }
    __syncthreads();
#pragma unroll
    for (int kk = 0; kk < 64; kk += 32) {
      bf16x8 af[2], bfr[4];
#pragma unroll
      for (int mi = 0; mi < 2; ++mi)
        af[mi] = *reinterpret_cast<const bf16x8*>(&sA[((wm << 5) + (mi << 4) + ln) * 64 + kk + (g << 3)]);
#pragma unroll
      for (int ni = 0; ni < 4; ++ni)
        bfr[ni] = *reinterpret_cast<const bf16x8*>(&sB[((wn << 6) + (ni << 4) + ln) * 64 + kk + (g << 3)]);
#pragma unroll
      for (int mi = 0; mi < 2; ++mi)
#pragma unroll
        for (int ni = 0; ni < 4; ++ni)
          acc[mi][ni] = __builtin_amdgcn_mfma_f32_16x16x32_bf16(af[mi], bfr[ni], acc[mi][ni], 0, 0, 0);
    }
    __syncthreads();
  }

#pragma unroll
  for (int mi = 0; mi < 2; ++mi) {
    const int o = o0 + (wm << 5) + (mi << 4) + (g << 2);
    const float b0 = bias[o], b1 = bias[o + 1], b2 = bias[o + 2], b3 = bias[o + 3];
#pragma unroll
    for (int ni = 0; ni < 4; ++ni) {
      const int n = n0 + (wn << 6) + (ni << 4) + ln;
      float* op = &out[((size_t)b * DATTN + o) * NPIX + n];
      op[0]        = acc[mi][ni][0] + b0;
      op[NPIX]     = acc[mi][ni][1] + b1;
      op[2 * NPIX] = acc[mi][ni][2] + b2;
      op[3 * NPIX] = acc[mi][ni][3] + b3;
    }
  }
}

extern "C" void kernel_launch(void* const* d_in, const int* in_sizes, int n_in,
                              void* d_out, int out_size, void* d_ws, size_t ws_size,
                              hipStream_t stream) {
  (void)in_sizes; (void)n_in; (void)out_size; (void)ws_size;
  const float* x      = (const float*)d_in[0];
  const float* w_qkv  = (const float*)d_in[1];
  const float* b_qkv  = (const float*)d_in[2];
  const float* w_proj = (const float*)d_in[3];
  const float* b_proj = (const float*)d_in[4];
  const float* rel    = (const float*)d_in[5];
  float* out = (float*)d_out;

  u16* xt    = (u16*)d_ws;                                   // 4 MB
  u16* wq_bf = xt + (size_t)BATCH * NPIX * CIN;              // 1.5 MB
  u16* wp_bf = wq_bf + (size_t)O_QKV * CIN;                  // 0.5 MB
  u16* qt    = wp_bf + (size_t)DATTN * DATTN;                // 4 MB
  u16* kt    = qt + (size_t)BATCH * HEADS * NPIX * DH;       // 4 MB
  u16* vt    = kt + (size_t)BATCH * HEADS * NPIX * DH;       // 4 MB
  u16* aout  = vt + (size_t)BATCH * HEADS * NPIX * DH;       // 4 MB

  prep_fused<<<1536, 256, 0, stream>>>(x, w_qkv, w_proj, xt, wq_bf, wp_bf);
  gemm_qkv_mfma<<<dim3(NPIX / 128, HEADS, BATCH), 256, 0, stream>>>(wq_bf, xt, b_qkv, qt, kt, vt);
  attn_mfma<<<1024, 128, 0, stream>>>(qt, kt, vt, rel, aout);
  gemm_proj_mfma<<<dim3(NPIX / 128, DATTN / 64, BATCH), 256, 0, stream>>>(wp_bf, aout, b_proj, out);
}

// Round 23
// 58.595 us; speedup vs baseline: 1.1008x; 1.1008x over previous
//
#include <hip/hip_runtime.h>
#include <cstdint>
#include <cstddef>

#define BATCH 4
#define CIN   512
#define NPIX  1024
#define HEADS 16
#define DH    32
#define DATTN 512
#define O_QKV 1536

typedef unsigned short u16;
typedef __bf16 bf16x4 __attribute__((ext_vector_type(4)));
typedef __bf16 bf16x8 __attribute__((ext_vector_type(8)));
typedef float  f32x4  __attribute__((ext_vector_type(4)));

typedef const __attribute__((address_space(1))) void g1_t;
typedef __attribute__((address_space(3))) void l3_t;

#if defined(__has_builtin)
#if __has_builtin(__builtin_amdgcn_exp2f)
#define EXP2(x) __builtin_amdgcn_exp2f(x)
#endif
#endif
#ifndef EXP2
#define EXP2(x) __expf((x) * 0.6931471805599453f)
#endif

__device__ __forceinline__ u16 f2bf(float f) {
  unsigned u = __float_as_uint(f);
  u += 0x7fffu + ((u >> 16) & 1u);
  return (u16)(u >> 16);
}

// async global->LDS, 16B per lane; lp must be wave-uniform (HW: base + lane*16)
__device__ __forceinline__ void gl_lds16(const void* gp, void* lp) {
  __builtin_amdgcn_global_load_lds((g1_t*)gp, (l3_t*)lp, 16, 0, 0);
}

// ---------------------------------------------------------------------------
// prep_fused: blocks 0..511 = x [B][C][N] f32 -> xt [B][N][C] bf16 (LDS
// transpose); blocks 512..1535 = w_qkv + w_proj f32 -> bf16. One launch.
// ---------------------------------------------------------------------------
__global__ __launch_bounds__(256) void prep_fused(const float* __restrict__ x,
                                                  const float* __restrict__ w1,
                                                  const float* __restrict__ w2,
                                                  u16* __restrict__ xt,
                                                  u16* __restrict__ o1,
                                                  u16* __restrict__ o2) {
  const int t = threadIdx.x;
  if (blockIdx.x < 512) {
    __shared__ float sT[64][65];
    const int q  = blockIdx.x;
    const int n0 = (q & 15) << 6;
    const int c0 = ((q >> 4) & 7) << 6;
    const int b  = q >> 7;
    const float* xb = x + ((size_t)b * CIN + c0) * NPIX + n0;
#pragma unroll
    for (int i = 0; i < 4; ++i) {
      int r   = i * 16 + (t >> 4);
      int col = (t & 15) << 2;
      float4 v = *reinterpret_cast<const float4*>(&xb[(size_t)r * NPIX + col]);
      sT[r][col + 0] = v.x; sT[r][col + 1] = v.y;
      sT[r][col + 2] = v.z; sT[r][col + 3] = v.w;
    }
    __syncthreads();
#pragma unroll
    for (int i = 0; i < 2; ++i) {
      int nl = t >> 2;
      int ch = (t & 3) + (i << 2);
      u16 tmp[8];
#pragma unroll
      for (int e = 0; e < 8; ++e) tmp[e] = f2bf(sT[(ch << 3) + e][nl]);
      *reinterpret_cast<uint4*>(&xt[((size_t)b * NPIX + n0 + nl) * CIN + c0 + (ch << 3)]) =
          *reinterpret_cast<uint4*>(tmp);
    }
  } else {
    const int idx = (blockIdx.x - 512) * 256 + t;   // float4 index
    const int n1 = (O_QKV * CIN) >> 2;              // 196608
    float4 v = (idx < n1) ? reinterpret_cast<const float4*>(w1)[idx]
                          : reinterpret_cast<const float4*>(w2)[idx - n1];
    uint2 pk = make_uint2((unsigned)f2bf(v.x) | ((unsigned)f2bf(v.y) << 16),
                          (unsigned)f2bf(v.z) | ((unsigned)f2bf(v.w) << 16));
    if (idx < n1) reinterpret_cast<uint2*>(o1)[idx] = pk;
    else          reinterpret_cast<uint2*>(o2)[idx - n1] = pk;
  }
}

// ---------------------------------------------------------------------------
// QKV GEMM (MFMA): M-tile=96 (one head), N-tile=128, BK=64, 4 waves.
// Epilogue: +bias, bf16; q PRE-SCALED by scale*log2e (attn uses exp2 domain).
// qt/kt [b][h][n][32], vt [b][h][d][n].
// ---------------------------------------------------------------------------
__global__ __launch_bounds__(256) void gemm_qkv_mfma(const u16* __restrict__ wq,
                                                     const u16* __restrict__ xt,
                                                     const float* __restrict__ bias,
                                                     u16* __restrict__ qt,
                                                     u16* __restrict__ kt,
                                                     u16* __restrict__ vt) {
  __shared__ __align__(16) u16 sA[96 * 64];
  __shared__ __align__(16) u16 sB[128 * 64];
  const int t  = threadIdx.x;
  const int w  = t >> 6, l = t & 63, g = l >> 4, ln = l & 15;
  const int n0 = blockIdx.x * 128;
  const int h  = blockIdx.y;
  const int b  = blockIdx.z;
  const int wm = w >> 1, wn = w & 1;

  const u16* wbase = wq + (size_t)h * 96 * CIN;
  const u16* xbase = xt + ((size_t)b * NPIX + n0) * CIN;

  f32x4 acc[3][4];
#pragma unroll
  for (int mi = 0; mi < 3; ++mi)
#pragma unroll
    for (int ni = 0; ni < 4; ++ni) acc[mi][ni] = {0.f, 0.f, 0.f, 0.f};

  for (int k0 = 0; k0 < CIN; k0 += 64) {
#pragma unroll
    for (int i = 0; i < 3; ++i) {
      int chunk = i * 256 + (w << 6) + l;
      gl_lds16(wbase + ((size_t)(chunk >> 3)) * CIN + k0 + ((chunk & 7) << 3),
               (char*)sA + i * 4096 + (w << 10));
    }
#pragma unroll
    for (int i = 0; i < 4; ++i) {
      int chunk = i * 256 + (w << 6) + l;
      gl_lds16(xbase + ((size_t)(chunk >> 3)) * CIN + k0 + ((chunk & 7) << 3),
               (char*)sB + i * 4096 + (w << 10));
    }
    __syncthreads();
#pragma unroll
    for (int kk = 0; kk < 64; kk += 32) {
      bf16x8 af[3], bfr[4];
#pragma unroll
      for (int mi = 0; mi < 3; ++mi)
        af[mi] = *reinterpret_cast<const bf16x8*>(&sA[(48 * wm + 16 * mi + ln) * 64 + kk + (g << 3)]);
#pragma unroll
      for (int ni = 0; ni < 4; ++ni)
        bfr[ni] = *reinterpret_cast<const bf16x8*>(&sB[((wn << 6) + (ni << 4) + ln) * 64 + kk + (g << 3)]);
#pragma unroll
      for (int mi = 0; mi < 3; ++mi)
#pragma unroll
        for (int ni = 0; ni < 4; ++ni)
          acc[mi][ni] = __builtin_amdgcn_mfma_f32_16x16x32_bf16(af[mi], bfr[ni], acc[mi][ni], 0, 0, 0);
    }
    __syncthreads();
  }

  const float QSC = 0.17677669529663687f * 1.4426950408889634f;  // scale*log2e
  const float* bh = bias + h * 96;
#pragma unroll
  for (int mi = 0; mi < 3; ++mi) {
    const int sec = 48 * wm + 16 * mi;
    const int rb  = sec + (g << 2);
    const float b0 = bh[rb + 0], b1 = bh[rb + 1], b2 = bh[rb + 2], b3 = bh[rb + 3];
#pragma unroll
    for (int ni = 0; ni < 4; ++ni) {
      const int n = n0 + (wn << 6) + (ni << 4) + ln;
      f32x4 a = acc[mi][ni];
      float v0 = a[0] + b0, v1 = a[1] + b1, v2 = a[2] + b2, v3 = a[3] + b3;
      if (sec < 32) { v0 *= QSC; v1 *= QSC; v2 *= QSC; v3 *= QSC; }
      u16 e0 = f2bf(v0), e1 = f2bf(v1), e2 = f2bf(v2), e3 = f2bf(v3);
      if (sec < 32) {
        const int d = sec + (g << 2);
        uint2 pk = make_uint2((unsigned)e0 | ((unsigned)e1 << 16),
                              (unsigned)e2 | ((unsigned)e3 << 16));
        *reinterpret_cast<uint2*>(&qt[(((size_t)(b * HEADS + h)) * NPIX + n) * DH + d]) = pk;
      } else if (sec < 64) {
        const int d = sec - 32 + (g << 2);
        uint2 pk = make_uint2((unsigned)e0 | ((unsigned)e1 << 16),
                              (unsigned)e2 | ((unsigned)e3 << 16));
        *reinterpret_cast<uint2*>(&kt[(((size_t)(b * HEADS + h)) * NPIX + n) * DH + d]) = pk;
      } else {
        const int d = sec - 64 + (g << 2);
        u16* vp = &vt[(((size_t)(b * HEADS + h)) * DH + d) * NPIX + n];
        vp[0] = e0; vp[NPIX] = e1; vp[2 * NPIX] = e2; vp[3 * NPIX] = e3;
      }
    }
  }
}

// ---------------------------------------------------------------------------
// MFMA flash attention v23 -- BATCH-PAIR waves + IN-BLOCK j-split.
// The two independently-verified gain conditions combined: (a) halved rel
// byte-stream (r17->r18 A/B: -15us) via 2 batches per wave sharing each rel
// load; (b) 16 waves/CU (every sub-16 config was slower; r20=(256,2) bound
// bug, r22=8 waves/CU).
// Block: 512 thr, 8 waves = 4 iw (16 i-rows) x 2 jh (j-halves of 512); each
// wave: 2 batches (bp*2+b2), 8 j-steps of 64, one __syncthreads/step.
// Grid 512 = 2 blocks/CU x 8 waves = 16 waves/CU. Decode (r20-verbatim):
// xcd=bid&7, sl=bid>>3; bp=sl&1 (siblings bid-dist 8 -> same XCD, adjacent
// -> rel L2 reuse), i0=((sl>>1)&15)<<6, h=(xcd<<1)|(sl>>5).
// Staging split across waves: wave (iw,jh) stages tile (jh, b2=iw>>1), K if
// iw even else V; 4 chunks/lane (c=i*64+l), r20 chunk formulas + jh offset.
// LDS: sK[2][2][2][2048] 32KB + sV same 32KB + sP[8][1024] 16KB = 80KB ->
// exactly 2 blocks/CU. (512,4): VGPR cap 128.
// jh partials merged IN-BLOCK via LDS scratch (r11-verified path, x2 batch).
// K LDS tile: [32 packed rows r=j>>1][8 slots 16B], slot^=(r&7)^((r>>3)&1).
// V LDS tile: [32 d][8 slots 16B], slot^=(d&7).
// sP per wave: [16 rows][8 slots 16B], slot^=(row&7); b64 half-slot writes.
// ---------------------------------------------------------------------------
__global__ __launch_bounds__(512, 4) void attn_mfma(const u16* __restrict__ qt,
                                                    const u16* __restrict__ kt,
                                                    const u16* __restrict__ vt,
                                                    const float* __restrict__ rel,
                                                    u16* __restrict__ aout) {
  __shared__ __align__(16) u16 sK[2][2][2][2048];  // [buf][jh][b2][tile] 32KB
  __shared__ __align__(16) u16 sV[2][2][2][2048];  // [buf][jh][b2][tile] 32KB
  __shared__ __align__(16) u16 sP[8][1024];        // per-wave              16KB

  const int t  = threadIdx.x;
  const int w  = t >> 6, l = t & 63, g = l >> 4, ln = l & 15;
  const int bid = blockIdx.x;
  const int xcd = bid & 7, sl = bid >> 3;   // sl 0..63
  const int bp  = sl & 1;                   // batch pair
  const int i0  = ((sl >> 1) & 15) << 6;
  const int h   = (xcd << 1) | (sl >> 5);
  const int iw  = w & 3;                    // i-segment (16 rows)
  const int jh  = w >> 2;                   // j-half (512 cols)

  const size_t bh0 = (size_t)((bp * 2 + 0) * HEADS + h);
  const size_t bh1 = (size_t)((bp * 2 + 1) * HEADS + h);

  // ---- staging assignment: wave (iw,jh) stages tile (jh, sb2=iw>>1);
  //      K if iw even, V if iw odd. 4 chunks/lane: c = i*64 + l.
  const int sb2  = iw >> 1;
  const bool isK = (iw & 1) == 0;
  const size_t sbh = sb2 ? bh1 : bh0;
  // per-chunk source offsets for i=0..3 (chunk c = i*64+l, r=c>>3, slot=c&7)
  const u16* src[4];
#pragma unroll
  for (int i = 0; i < 4; ++i) {
    const int c = i * 64 + l;
    const int r = c >> 3, slot = c & 7;
    if (isK) {
      const int kc = slot ^ (r & 7) ^ ((r >> 3) & 1);
      src[i] = kt + sbh * NPIX * DH +
               ((size_t)((jh << 9) + ((r << 1) | (kc >> 2)))) * DH + ((kc & 3) << 3);
    } else {
      const int vc = slot ^ (r & 7);
      src[i] = vt + (sbh * DH + r) * NPIX + (jh << 9) + (vc << 3);
    }
  }
  // LDS tile base (bytes): [buf p][jh][sb2] -> issue i adds i*1024
  char* dstBase = isK ? (char*)&sK[0][jh][sb2][0] : (char*)&sV[0][jh][sb2][0];
  const size_t sstep = isK ? 2048 : 64;     // u16 per j-step in source

#define STAGE(s_, p_) do {                                                   \
    gl_lds16(src[0] + (size_t)(s_) * sstep, dstBase + (p_) * 16384);         \
    gl_lds16(src[1] + (size_t)(s_) * sstep, dstBase + (p_) * 16384 + 1024);  \
    gl_lds16(src[2] + (size_t)(s_) * sstep, dstBase + (p_) * 16384 + 2048);  \
    gl_lds16(src[3] + (size_t)(s_) * sstep, dstBase + (p_) * 16384 + 3072);  \
  } while (0)

  STAGE(0, 0);

  // Q fragments (pre-scaled by scale*log2e): lane -> row i0+16*iw+ln, k=8g..
  bf16x8 qf0 = *reinterpret_cast<const bf16x8*>(
      qt + (bh0 * NPIX + i0 + (iw << 4) + ln) * DH + (g << 3));
  bf16x8 qf1 = *reinterpret_cast<const bf16x8*>(
      qt + (bh1 * NPIX + i0 + (iw << 4) + ln) * DH + (g << 3));

  // rel: rows i0+16iw+4g+v, cols jh*512 + s*64 + 4ln + (0..3) -- ONCE, x2 use
  const float* relp = rel + ((size_t)h * NPIX + i0 + (iw << 4) + (g << 2)) * NPIX +
                      (jh << 9) + (ln << 2);
  f32x4 relA4[4], relB4[4];
#pragma unroll
  for (int v = 0; v < 4; ++v)
    relA4[v] = *reinterpret_cast<const f32x4*>(relp + (size_t)v * NPIX);

  f32x4 vzero = {0.f, 0.f, 0.f, 0.f};
  f32x4 accO0[2] = {vzero, vzero};
  f32x4 accO1[2] = {vzero, vzero};
  f32x4 l_lane0 = vzero, l_lane1 = vzero;

  u16* sPw = &sP[w][0];
  const float LOG2E = 1.4426950408889634f;

  for (int s = 0; s < 8; ++s) {
    const int p = s & 1;
    __syncthreads();                        // buf p staged; buf p^1 free
    if (s < 7) {
      STAGE(s + 1, p ^ 1);
#pragma unroll
      for (int v = 0; v < 4; ++v)
        relB4[v] = *reinterpret_cast<const f32x4*>(relp + (size_t)v * NPIX + ((s + 1) << 6));
    }

#pragma unroll
    for (int b2 = 0; b2 < 2; ++b2) {
      const u16* Kb = &sK[p][jh][b2][0];
      const u16* Vb = &sV[p][jh][b2][0];
      const bf16x8 qf = b2 ? qf1 : qf0;

      // ---- S' = Q'^T K: fragment jj covers cols j = 4*ln + jj ----
      f32x4 sfr[4];
      __builtin_amdgcn_s_setprio(1);
#pragma unroll
      for (int jj = 0; jj < 4; ++jj) {
        const int r  = (ln << 1) + (jj >> 1);
        const int ks = ((((jj & 1) << 2) | g) ^ (r & 7)) ^ ((r >> 3) & 1);
        bf16x8 kf = *reinterpret_cast<const bf16x8*>(Kb + r * 64 + ks * 8);
        sfr[jj] = __builtin_amdgcn_mfma_f32_16x16x32_bf16(qf, kf, vzero, 0, 0, 0);
      }
      __builtin_amdgcn_s_setprio(0);

      // ---- P = exp2(S' + rel*log2e); swizzled b64 write per row ----
#pragma unroll
      for (int v = 0; v < 4; ++v) {
        float p0 = EXP2(fmaf(relA4[v][0], LOG2E, sfr[0][v]));
        float p1 = EXP2(fmaf(relA4[v][1], LOG2E, sfr[1][v]));
        float p2 = EXP2(fmaf(relA4[v][2], LOG2E, sfr[2][v]));
        float p3 = EXP2(fmaf(relA4[v][3], LOG2E, sfr[3][v]));
        if (b2) l_lane1[v] += (p0 + p1) + (p2 + p3);
        else    l_lane0[v] += (p0 + p1) + (p2 + p3);
        bf16x4 pk;
        pk[0] = (__bf16)p0; pk[1] = (__bf16)p1; pk[2] = (__bf16)p2; pk[3] = (__bf16)p3;
        const int rw = (g << 2) + v;
        *reinterpret_cast<bf16x4*>(
            sPw + rw * 64 + ((((ln >> 1) ^ (rw & 7)) << 3) | ((ln & 1) << 2))) = pk;
      }

      // ---- PV: acc[dc] += P(kc) x V(kc,dc) ----
      __builtin_amdgcn_s_setprio(1);
#pragma unroll
      for (int kc = 0; kc < 2; ++kc) {
        const int lc = (kc << 2) | g;
        bf16x8 pa = *reinterpret_cast<const bf16x8*>(sPw + ln * 64 + ((lc ^ (ln & 7)) << 3));
#pragma unroll
        for (int dc = 0; dc < 2; ++dc) {
          const int d  = (dc << 4) + ln;
          const int vs = lc ^ (d & 7);
          bf16x8 vf = *reinterpret_cast<const bf16x8*>(Vb + d * 64 + vs * 8);
          if (b2) accO1[dc] = __builtin_amdgcn_mfma_f32_16x16x32_bf16(pa, vf, accO1[dc], 0, 0, 0);
          else    accO0[dc] = __builtin_amdgcn_mfma_f32_16x16x32_bf16(pa, vf, accO0[dc], 0, 0, 0);
        }
      }
      __builtin_amdgcn_s_setprio(0);
    }

    if (s < 7) {
#pragma unroll
      for (int v = 0; v < 4; ++v) relA4[v] = relB4[v];
    }
  }
#undef STAGE

  // ---- merge jh halves IN-BLOCK (both batches), finalize (jh==0 writes) ----
  __syncthreads();
  float* mrg = (float*)&sK[0][0][0][0];     // 24.5KB scratch over sK (32KB)
  if (jh == 1) {
    float* mp = mrg + ((size_t)((iw << 6) + l)) * 24;
    *reinterpret_cast<f32x4*>(mp +  0) = accO0[0];
    *reinterpret_cast<f32x4*>(mp +  4) = accO0[1];
    *reinterpret_cast<f32x4*>(mp +  8) = l_lane0;
    *reinterpret_cast<f32x4*>(mp + 12) = accO1[0];
    *reinterpret_cast<f32x4*>(mp + 16) = accO1[1];
    *reinterpret_cast<f32x4*>(mp + 20) = l_lane1;
  }
  __syncthreads();
  if (jh == 0) {
    const float* mp = mrg + ((size_t)((iw << 6) + l)) * 24;
    f32x4 o00 = accO0[0] + *reinterpret_cast<const f32x4*>(mp + 0);
    f32x4 o01 = accO0[1] + *reinterpret_cast<const f32x4*>(mp + 4);
    f32x4 lv0 = l_lane0 + *reinterpret_cast<const f32x4*>(mp + 8);
    f32x4 o10 = accO1[0] + *reinterpret_cast<const f32x4*>(mp + 12);
    f32x4 o11 = accO1[1] + *reinterpret_cast<const f32x4*>(mp + 16);
    f32x4 lv1 = l_lane1 + *reinterpret_cast<const f32x4*>(mp + 20);
#pragma unroll
    for (int v = 0; v < 4; ++v) {
      float ls = lv0[v];
      ls += __shfl_xor(ls, 1);
      ls += __shfl_xor(ls, 2);
      ls += __shfl_xor(ls, 4);
      ls += __shfl_xor(ls, 8);
      const float inv = 1.f / ls;
      const size_t row = (size_t)(bp * 2 + 0) * NPIX + i0 + (iw << 4) + (g << 2) + v;
      aout[row * DATTN + (h << 5) + ln]      = f2bf(o00[v] * inv);
      aout[row * DATTN + (h << 5) + 16 + ln] = f2bf(o01[v] * inv);
    }
#pragma unroll
    for (int v = 0; v < 4; ++v) {
      float ls = lv1[v];
      ls += __shfl_xor(ls, 1);
      ls += __shfl_xor(ls, 2);
      ls += __shfl_xor(ls, 4);
      ls += __shfl_xor(ls, 8);
      const float inv = 1.f / ls;
      const size_t row = (size_t)(bp * 2 + 1) * NPIX + i0 + (iw << 4) + (g << 2) + v;
      aout[row * DATTN + (h << 5) + ln]      = f2bf(o10[v] * inv);
      aout[row * DATTN + (h << 5) + 16 + ln] = f2bf(o11[v] * inv);
    }
  }
}

// ---------------------------------------------------------------------------
// Proj GEMM (MFMA): out[b][o][n] = sum_k Wp[o,k] * A[b][n][k] + bias[o], f32 out.
// ---------------------------------------------------------------------------
__global__ __launch_bounds__(256) void gemm_proj_mfma(const u16* __restrict__ wp,
                                                      const u16* __restrict__ at,
                                                      const float* __restrict__ bias,
                                                      float* __restrict__ out) {
  __shared__ __align__(16) u16 sA[64 * 64];
  __shared__ __align__(16) u16 sB[128 * 64];
  const int t  = threadIdx.x;
  const int w  = t >> 6, l = t & 63, g = l >> 4, ln = l & 15;
  const int n0 = blockIdx.x * 128;
  const int o0 = blockIdx.y * 64;
  const int b  = blockIdx.z;
  const int wm = w >> 1, wn = w & 1;

  const u16* wbase = wp + (size_t)o0 * DATTN;
  const u16* abase = at + ((size_t)b * NPIX + n0) * DATTN;

  f32x4 acc[2][4];
#pragma unroll
  for (int mi = 0; mi < 2; ++mi)
#pragma unroll
    for (int ni = 0; ni < 4; ++ni) acc[mi][ni] = {0.f, 0.f, 0.f, 0.f};

  for (int k0 = 0; k0 < DATTN; k0 += 64) {
#pragma unroll
    for (int i = 0; i < 2; ++i) {
      int chunk = i * 256 + (w << 6) + l;
      gl_lds16(wbase + ((size_t)(chunk >> 3)) * DATTN + k0 + ((chunk & 7) << 3),
               (char*)sA + i * 4096 + (w << 10));
    }
#pragma unroll
    for (int i = 0; i < 4; ++i) {
      int chunk = i * 256 + (w << 6) + l;
      gl_lds16(abase + ((size_t)(chunk >> 3)) * DATTN + k0 + ((chunk & 7) << 3),
               (char*)sB + i * 4096 + (w << 10));
    }
    __syncthreads();
#pragma unroll
    for (int kk = 0; kk < 64; kk += 32) {
      bf16x8 af[2], bfr[4];
#pragma unroll
      for (int mi = 0; mi < 2; ++mi)
        af[mi] = *reinterpret_cast<const bf16x8*>(&sA[((wm << 5) + (mi << 4) + ln) * 64 + kk + (g << 3)]);
#pragma unroll
      for (int ni = 0; ni < 4; ++ni)
        bfr[ni] = *reinterpret_cast<const bf16x8*>(&sB[((wn << 6) + (ni << 4) + ln) * 64 + kk + (g << 3)]);
#pragma unroll
      for (int mi = 0; mi < 2; ++mi)
#pragma unroll
        for (int ni = 0; ni < 4; ++ni)
          acc[mi][ni] = __builtin_amdgcn_mfma_f32_16x16x32_bf16(af[mi], bfr[ni], acc[mi][ni], 0, 0, 0);
    }
    __syncthreads();
  }

#pragma unroll
  for (int mi = 0; mi < 2; ++mi) {
    const int o = o0 + (wm << 5) + (mi << 4) + (g << 2);
    const float b0 = bias[o], b1 = bias[o + 1], b2 = bias[o + 2], b3 = bias[o + 3];
#pragma unroll
    for (int ni = 0; ni < 4; ++ni) {
      const int n = n0 + (wn << 6) + (ni << 4) + ln;
      float* op = &out[((size_t)b * DATTN + o) * NPIX + n];
      op[0]        = acc[mi][ni][0] + b0;
      op[NPIX]     = acc[mi][ni][1] + b1;
      op[2 * NPIX] = acc[mi][ni][2] + b2;
      op[3 * NPIX] = acc[mi][ni][3] + b3;
    }
  }
}

extern "C" void kernel_launch(void* const* d_in, const int* in_sizes, int n_in,
                              void* d_out, int out_size, void* d_ws, size_t ws_size,
                              hipStream_t stream) {
  (void)in_sizes; (void)n_in; (void)out_size; (void)ws_size;
  const float* x      = (const float*)d_in[0];
  const float* w_qkv  = (const float*)d_in[1];
  const float* b_qkv  = (const float*)d_in[2];
  const float* w_proj = (const float*)d_in[3];
  const float* b_proj = (const float*)d_in[4];
  const float* rel    = (const float*)d_in[5];
  float* out = (float*)d_out;

  u16* xt    = (u16*)d_ws;                                   // 4 MB
  u16* wq_bf = xt + (size_t)BATCH * NPIX * CIN;              // 1.5 MB
  u16* wp_bf = wq_bf + (size_t)O_QKV * CIN;                  // 0.5 MB
  u16* qt    = wp_bf + (size_t)DATTN * DATTN;                // 4 MB
  u16* kt    = qt + (size_t)BATCH * HEADS * NPIX * DH;       // 4 MB
  u16* vt    = kt + (size_t)BATCH * HEADS * NPIX * DH;       // 4 MB
  u16* aout  = vt + (size_t)BATCH * HEADS * NPIX * DH;       // 4 MB

  prep_fused<<<1536, 256, 0, stream>>>(x, w_qkv, w_proj, xt, wq_bf, wp_bf);
  gemm_qkv_mfma<<<dim3(NPIX / 128, HEADS, BATCH), 256, 0, stream>>>(wq_bf, xt, b_qkv, qt, kt, vt);
  attn_mfma<<<512, 512, 0, stream>>>(qt, kt, vt, rel, aout);
  gemm_proj_mfma<<<dim3(NPIX / 128, DATTN / 64, BATCH), 256, 0, stream>>>(wp_bf, aout, b_proj, out);
}